// Round 9
// baseline (1038.642 us; speedup 1.0000x reference)
//
#include <hip/hip_runtime.h>
#include <math.h>

constexpr int Cc = 3, Hh = 256;
constexpr int NX = 393216;   // 2*3*256*256
constexpr int R = 8;         // rows per block
constexpr int NBLK = 192;    // 6 images * 32 tiles (<= 256 CUs: 1 block/CU)
constexpr int KSTEPS = 50;
constexpr int NSLOT = 3;

using u64 = unsigned long long;
constexpr u64 SENT = 0x8000000080000000ull;   // (-0.0f,-0.0f): unreachable payload
constexpr u64 CNT1 = 1ull << 57;              // count increment (top 7 bits)
constexpr u64 MASK57 = CNT1 - 1ull;
constexpr float FPS = 16777216.0f;            // 2^24 fixed-point scale
constexpr float FPSI = 1.0f / 16777216.0f;

__device__ __forceinline__ float4 ld4(const float* p, int i) { return ((const float4*)p)[i]; }
__device__ __forceinline__ void st4(float* p, int i, float4 v) { ((float4*)p)[i] = v; }
__device__ __forceinline__ float4 mk4(float a, float b, float c, float d) { return make_float4(a, b, c, d); }

__device__ __forceinline__ u64 ldq(const u64* p) {
    return __hip_atomic_load(p, __ATOMIC_RELAXED, __HIP_MEMORY_SCOPE_AGENT);
}
__device__ __forceinline__ void stq(u64* p, u64 v) {
    __hip_atomic_store(p, v, __ATOMIC_RELAXED, __HIP_MEMORY_SCOPE_AGENT);
}
__device__ __forceinline__ void adq(u64* p, u64 v) {
    __hip_atomic_fetch_add(p, v, __ATOMIC_RELAXED, __HIP_MEMORY_SCOPE_AGENT);
}
__device__ __forceinline__ void pub4(u64* w, float4 v) {
    union { float f[2]; u64 q; } a, b;
    a.f[0] = v.x; a.f[1] = v.y; b.f[0] = v.z; b.f[1] = v.w;
    stq(w, a.q); stq(w + 1, b.q);
}
__device__ __forceinline__ float4 unp(u64 lo, u64 hi) {
    union { u64 q; float f[2]; } a, b; a.q = lo; b.q = hi;
    return make_float4(a.f[0], a.f[1], b.f[0], b.f[1]);
}
// H layout: u64 H[NSLOT][NBLK][4][128]; rows: 0=v0 last, 1=v0 first, 2=v1 first, 3=x first
__device__ __forceinline__ u64* recq(u64* H, int slot, int blk, int row) {
    return H + ((((size_t)slot * NBLK + blk) * 4 + row) << 7);
}

__global__ void init_ws(u64* H, u64* parts) {
    int i = blockIdx.x * 256 + threadIdx.x;
    if (i < NSLOT * NBLK * 4 * 128) H[i] = SENT;
    if (i < (KSTEPS + 1) * 8) parts[i] = 0ull;
}

__global__ void __launch_bounds__(256) cp_persist(
    const float* __restrict__ y, const float* __restrict__ lambd,
    float* __restrict__ xout, float* __restrict__ xtout, float* __restrict__ uout,
    u64* __restrict__ H, u64* __restrict__ parts)
{
    __shared__ float sxt[9 * 256];
    __shared__ float sv0[8 * 256];
    __shared__ float2 pw[4];
    const int tid = threadIdx.x;
    const int blk = blockIdx.x;
    const int bc = blk >> 5;           // image index [0,6)
    const int tile = blk & 31;         // [0,32)
    const int r0 = tile * R;
    const int c4 = tid & 63;
    const int trow = tid >> 6;         // [0,4)
    const int b = (bc >= Cc) ? 1 : 0;

    const float lamb = expf(lambd[0]);

    float4 yv[2], xreg[2], v0[2], v1[2], u0[2], u1[2], xtp[2];
    float4 yhalo = mk4(0.f, 0.f, 0.f, 0.f);
    if (trow == 0 && tile < 31) yhalo = ld4(y, bc * 16384 + (r0 + 8) * 64 + c4);

    // ---------------- init (step 0): x=y, v = nabla(y); publish; norm-add ----------------
    {
        float pa0 = 0.f, pa1 = 0.f;
        #pragma unroll
        for (int k = 0; k < 2; ++k) {
            const int rr = trow + 4 * k;
            const int gh = r0 + rr;
            const int j4 = bc * 16384 + gh * 64 + c4;
            yv[k] = ld4(y, j4);
            xreg[k] = yv[k];
            float4 dh = mk4(0.f, 0.f, 0.f, 0.f);
            if (gh < Hh - 1) {
                float4 yn = ld4(y, j4 + 64);
                dh.x = yn.x - yv[k].x; dh.y = yn.y - yv[k].y;
                dh.z = yn.z - yv[k].z; dh.w = yn.w - yv[k].w;
            }
            float4 dw;
            dw.x = yv[k].y - yv[k].x; dw.y = yv[k].z - yv[k].y; dw.z = yv[k].w - yv[k].z;
            float ynx = __shfl_down(yv[k].x, 1, 64);
            dw.w = (c4 < 63) ? (ynx - yv[k].w) : 0.f;
            v0[k] = dh; v1[k] = dw;
            ((float4*)(sv0 + rr * 256))[c4] = dh;
            pa0 += dh.x*dh.x + dh.y*dh.y + dh.z*dh.z + dh.w*dh.w;
            pa1 += dw.x*dw.x + dw.y*dw.y + dw.z*dw.z + dw.w*dw.w;
        }
        if (trow == 0) {
            pub4(recq(H, 0, blk, 1) + 2 * c4, v0[0]);
            pub4(recq(H, 0, blk, 2) + 2 * c4, v1[0]);
            pub4(recq(H, 0, blk, 3) + 2 * c4, xreg[0]);
        }
        if (trow == 3) pub4(recq(H, 0, blk, 0) + 2 * c4, v0[1]);   // row r0+7
        #pragma unroll
        for (int m = 1; m < 64; m <<= 1) {
            pa0 += __shfl_xor(pa0, m, 64);
            pa1 += __shfl_xor(pa1, m, 64);
        }
        if (c4 == 0) pw[trow] = make_float2(pa0, pa1);
        __syncthreads();
        if (tid == 0) {
            float q0 = pw[0].x + pw[1].x + pw[2].x + pw[3].x;
            float q1 = pw[0].y + pw[1].y + pw[2].y + pw[3].y;
            adq(parts + 2 * b,     CNT1 + (u64)(q0 * FPS));
            adq(parts + 2 * b + 1, CNT1 + (u64)(q1 * FPS));
        }
    }

    float sigma = 0.20412414523193150818f;   // 0.5/sqrt(6)
    float tau   = sigma;

    for (int s = 1; s <= KSTEPS; ++s) {
        const int p = (s - 1) % NSLOT;
        const u64* cw = parts + (size_t)(s - 1) * 8 + 2 * b;
        u64 w0, w1;
        float4 vmtop = mk4(0.f, 0.f, 0.f, 0.f);
        float4 v0h = vmtop, v1h = vmtop, xoh = vmtop;

        // ------- poll: count words (all waves) + own halo words (wave 0) -------
        if (trow == 0) {
            const u64* rm = recq(H, p, blk - 1, 0) + 2 * c4;   // valid only if tile>0
            const u64* r1 = recq(H, p, blk + 1, 1) + 2 * c4;   // valid only if tile<31
            const u64* r2 = recq(H, p, blk + 1, 2) + 2 * c4;
            const u64* r3 = recq(H, p, blk + 1, 3) + 2 * c4;
            u64 m0 = SENT, m1 = SENT, h0 = SENT, h1 = SENT, h2 = SENT, h3 = SENT, h4 = SENT, h5 = SENT;
            for (;;) {
                w0 = ldq(cw); w1 = ldq(cw + 1);
                bool ok = ((w0 >> 57) == 96) && ((w1 >> 57) == 96);
                if (tile > 0) {
                    m0 = ldq(rm); m1 = ldq(rm + 1);
                    ok = ok && (m0 != SENT) && (m1 != SENT);
                }
                if (tile < 31) {
                    h0 = ldq(r1); h1 = ldq(r1 + 1);
                    h2 = ldq(r2); h3 = ldq(r2 + 1);
                    h4 = ldq(r3); h5 = ldq(r3 + 1);
                    ok = ok && (h0 != SENT) && (h1 != SENT) && (h2 != SENT)
                            && (h3 != SENT) && (h4 != SENT) && (h5 != SENT);
                }
                if (__all(ok)) break;
                __builtin_amdgcn_s_sleep(1);
            }
            if (tile > 0)  vmtop = unp(m0, m1);
            if (tile < 31) { v0h = unp(h0, h1); v1h = unp(h2, h3); xoh = unp(h4, h5); }
        } else {
            for (;;) {
                w0 = ldq(cw); w1 = ldq(cw + 1);
                if (__all(((w0 >> 57) == 96) && ((w1 >> 57) == 96))) break;
                __builtin_amdgcn_s_sleep(1);
            }
        }
        asm volatile("" ::: "memory");

        // ------- resets: each publisher resets exactly its own future-publish words -------
        if (s < KSTEPS) {
            u64* rb = recq(H, (s + 1) % NSLOT, blk, 0);
            if (trow == 0) {
                #pragma unroll
                for (int r = 1; r < 4; ++r) {
                    stq(rb + (r << 7) + 2 * c4, SENT);
                    stq(rb + (r << 7) + 2 * c4 + 1, SENT);
                }
            } else if (trow == 3) {
                stq(rb + 2 * c4, SENT);
                stq(rb + 2 * c4 + 1, SENT);
            }
        }

        // scales straight from the polled words (integer sum -> deterministic)
        const float s0 = lamb / fmaxf(sqrtf((float)(w0 & MASK57) * FPSI), lamb);
        const float s1 = lamb / fmaxf(sqrtf((float)(w1 & MASK57) * FPSI), lamb);
        const float chi = 1.0f / sqrtf(1.0f + tau);
        const float inv = 1.0f / (1.0f + tau);
        const float opc = 1.0f + chi;
        const int q = s % NSLOT;

        // ---------------- phase B (step s-1) ----------------
        #pragma unroll
        for (int k = 0; k < 2; ++k) {
            const int rr = trow + 4 * k;
            const int gh = r0 + rr;
            float4 uu0, uu1;
            uu0.x = v0[k].x*s0; uu0.y = v0[k].y*s0; uu0.z = v0[k].z*s0; uu0.w = v0[k].w*s0;
            uu1.x = v1[k].x*s1; uu1.y = v1[k].y*s1; uu1.z = v1[k].z*s1; uu1.w = v1[k].w*s1;
            float4 vm = (k == 0) ? ((trow > 0) ? ((float4*)(sv0 + (trow - 1) * 256))[c4] : vmtop)
                                 : ((float4*)(sv0 + (trow + 3) * 256))[c4];
            float nt0 = 0.f, nt1 = 0.f, nt2 = 0.f, nt3 = 0.f;
            if (gh > 0) { nt0 += vm.x*s0; nt1 += vm.y*s0; nt2 += vm.z*s0; nt3 += vm.w*s0; }
            if (gh < Hh - 1) { nt0 -= uu0.x; nt1 -= uu0.y; nt2 -= uu0.z; nt3 -= uu0.w; }
            float ul = __shfl_up(uu1.w, 1, 64);
            if (c4 > 0) nt0 += ul;
            nt1 += uu1.x; nt2 += uu1.y; nt3 += uu1.z;
            nt0 -= uu1.x; nt1 -= uu1.y; nt2 -= uu1.z;
            if (c4 < 63) nt3 -= uu1.w;
            float4 xp;
            xp.x = (xreg[k].x + tau * (yv[k].x - nt0)) * inv;
            xp.y = (xreg[k].y + tau * (yv[k].y - nt1)) * inv;
            xp.z = (xreg[k].z + tau * (yv[k].z - nt2)) * inv;
            xp.w = (xreg[k].w + tau * (yv[k].w - nt3)) * inv;
            xtp[k].x = opc * xp.x - chi * xreg[k].x;
            xtp[k].y = opc * xp.y - chi * xreg[k].y;
            xtp[k].z = opc * xp.z - chi * xreg[k].z;
            xtp[k].w = opc * xp.w - chi * xreg[k].w;
            u0[k] = uu0; u1[k] = uu1;
            if (s == KSTEPS) {
                const int j4 = bc * 16384 + gh * 64 + c4;
                const int iv4 = bc * 32768 + gh * 64 + c4;
                st4(xout, j4, xp);
                st4(xtout, j4, xtp[k]);
                st4(uout, iv4, uu0);
                st4(uout, iv4 + 16384, uu1);
            } else {
                xreg[k] = xp;
                if (rr >= 1) ((float4*)(sxt + rr * 256))[c4] = xtp[k];
                if (trow == 0 && k == 0) {
                    // order: prev-step resets of slot q complete before republishing into q.
                    // outstanding newest 6 = this step's resets (different slot) -> allowed.
                    asm volatile("s_waitcnt vmcnt(6)" ::: "memory");
                    pub4(recq(H, q, blk, 3) + 2 * c4, xp);
                }
            }
        }
        if (s == KSTEPS) break;

        // ---- redundant halo row r0+8 (wave 0, tile<31; always interior in h) ----
        if (trow == 0 && tile < 31) {
            float4 h0, h1;
            h0.x = v0h.x*s0; h0.y = v0h.y*s0; h0.z = v0h.z*s0; h0.w = v0h.w*s0;
            h1.x = v1h.x*s1; h1.y = v1h.y*s1; h1.z = v1h.z*s1; h1.w = v1h.w*s1;
            float4 vmh = ((float4*)(sv0 + 7 * 256))[c4];
            float nt0 = vmh.x*s0 - h0.x, nt1 = vmh.y*s0 - h0.y,
                  nt2 = vmh.z*s0 - h0.z, nt3 = vmh.w*s0 - h0.w;
            float hul = __shfl_up(h1.w, 1, 64);
            if (c4 > 0) nt0 += hul;
            nt1 += h1.x; nt2 += h1.y; nt3 += h1.z;
            nt0 -= h1.x; nt1 -= h1.y; nt2 -= h1.z;
            if (c4 < 63) nt3 -= h1.w;
            float4 xph, xth;
            xph.x = (xoh.x + tau * (yhalo.x - nt0)) * inv;
            xph.y = (xoh.y + tau * (yhalo.y - nt1)) * inv;
            xph.z = (xoh.z + tau * (yhalo.z - nt2)) * inv;
            xph.w = (xoh.w + tau * (yhalo.w - nt3)) * inv;
            xth.x = opc * xph.x - chi * xoh.x;
            xth.y = opc * xph.y - chi * xoh.y;
            xth.z = opc * xph.z - chi * xoh.z;
            xth.w = opc * xph.w - chi * xoh.w;
            ((float4*)(sxt + 8 * 256))[c4] = xth;
        }
        __syncthreads();

        // ---------------- phase A (step s); wave 3 does k=1 first (early last-row pub) ----
        const float sigs = sigma / chi;
        float pa0 = 0.f, pa1 = 0.f;
        const int kfirst = (trow == 3) ? 1 : 0;
        #pragma unroll
        for (int kk = 0; kk < 2; ++kk) {
            const int k = kfirst ^ kk;
            const int rr = trow + 4 * k;
            const int gh = r0 + rr;
            float4 dh = mk4(0.f, 0.f, 0.f, 0.f);
            if (gh < Hh - 1) {
                float4 xn = ((const float4*)(sxt + (rr + 1) * 256))[c4];
                dh.x = xn.x - xtp[k].x; dh.y = xn.y - xtp[k].y;
                dh.z = xn.z - xtp[k].z; dh.w = xn.w - xtp[k].w;
            }
            float4 dw;
            dw.x = xtp[k].y - xtp[k].x; dw.y = xtp[k].z - xtp[k].y; dw.z = xtp[k].w - xtp[k].z;
            float xnx = __shfl_down(xtp[k].x, 1, 64);
            dw.w = (c4 < 63) ? (xnx - xtp[k].w) : 0.f;
            v0[k].x = fmaf(sigs, dh.x, u0[k].x); v0[k].y = fmaf(sigs, dh.y, u0[k].y);
            v0[k].z = fmaf(sigs, dh.z, u0[k].z); v0[k].w = fmaf(sigs, dh.w, u0[k].w);
            v1[k].x = fmaf(sigs, dw.x, u1[k].x); v1[k].y = fmaf(sigs, dw.y, u1[k].y);
            v1[k].z = fmaf(sigs, dw.z, u1[k].z); v1[k].w = fmaf(sigs, dw.w, u1[k].w);
            ((float4*)(sv0 + rr * 256))[c4] = v0[k];
            pa0 += v0[k].x*v0[k].x + v0[k].y*v0[k].y + v0[k].z*v0[k].z + v0[k].w*v0[k].w;
            pa1 += v1[k].x*v1[k].x + v1[k].y*v1[k].y + v1[k].z*v1[k].z + v1[k].w*v1[k].w;
            if (trow == 0 && k == 0) {
                pub4(recq(H, q, blk, 1) + 2 * c4, v0[0]);
                pub4(recq(H, q, blk, 2) + 2 * c4, v1[0]);
            }
            if (trow == 3 && k == 1) {
                asm volatile("s_waitcnt vmcnt(2)" ::: "memory");   // prev resets of row 0 done
                pub4(recq(H, q, blk, 0) + 2 * c4, v0[1]);
            }
        }
        #pragma unroll
        for (int m = 1; m < 64; m <<= 1) {
            pa0 += __shfl_xor(pa0, m, 64);
            pa1 += __shfl_xor(pa1, m, 64);
        }
        if (c4 == 0) pw[trow] = make_float2(pa0, pa1);
        __syncthreads();
        if (tid == 0) {
            float q0 = pw[0].x + pw[1].x + pw[2].x + pw[3].x;
            float q1 = pw[0].y + pw[1].y + pw[2].y + pw[3].y;
            adq(parts + (size_t)s * 8 + 2 * b,     CNT1 + (u64)(q0 * FPS));
            adq(parts + (size_t)s * 8 + 2 * b + 1, CNT1 + (u64)(q1 * FPS));
        }

        tau *= chi;
        sigma = sigs;
    }
}

extern "C" void kernel_launch(void* const* d_in, const int* in_sizes, int n_in,
                              void* d_out, int out_size, void* d_ws, size_t ws_size,
                              hipStream_t stream) {
    (void)in_sizes; (void)n_in; (void)out_size; (void)ws_size;
    const float* y     = (const float*)d_in[0];
    const float* lambd = (const float*)d_in[1];
    float* xout  = (float*)d_out;       // [0, NX)
    float* xtout = xout + NX;           // [NX, 2NX)
    float* uout  = xout + 2 * NX;       // [2NX, 2NX+NU)

    u64* H     = (u64*)d_ws;                         // [NSLOT][NBLK][4][128]
    u64* parts = H + (size_t)NSLOT * NBLK * 4 * 128; // [KSTEPS+1][8] (count+sum words)

    init_ws<<<(NSLOT * NBLK * 4 * 128 + 255) / 256, 256, 0, stream>>>(H, parts);
    cp_persist<<<NBLK, 256, 0, stream>>>(y, lambd, xout, xtout, uout, H, parts);
}

// Round 10
// 482.303 us; speedup vs baseline: 2.1535x; 2.1535x over previous
//
#include <hip/hip_runtime.h>
#include <math.h>

constexpr int Cc = 3, Hh = 256;
constexpr int NX = 393216;   // 2*3*256*256
constexpr int R = 8;         // rows per block
constexpr int NBLK = 192;    // 6 images * 32 tiles (<= 256 CUs: 1 block/CU)
constexpr int KSTEPS = 50;
constexpr int NSLOT = 3;
constexpr int PWRD = NBLK * 4;   // per-step parts words (one per wave) = 768

using u64 = unsigned long long;
constexpr u64 SENT = 0x8000000080000000ull;   // (-0.0f,-0.0f): unreachable payload

__device__ __forceinline__ float4 ld4(const float* p, int i) { return ((const float4*)p)[i]; }
__device__ __forceinline__ void st4(float* p, int i, float4 v) { ((float4*)p)[i] = v; }
__device__ __forceinline__ float4 mk4(float a, float b, float c, float d) { return make_float4(a, b, c, d); }

__device__ __forceinline__ u64 ldq(const u64* p) {
    return __hip_atomic_load(p, __ATOMIC_RELAXED, __HIP_MEMORY_SCOPE_AGENT);
}
__device__ __forceinline__ void stq(u64* p, u64 v) {
    __hip_atomic_store(p, v, __ATOMIC_RELAXED, __HIP_MEMORY_SCOPE_AGENT);
}
__device__ __forceinline__ void pub4(u64* w, float4 v) {
    union { float f[2]; u64 q; } a, b;
    a.f[0] = v.x; a.f[1] = v.y; b.f[0] = v.z; b.f[1] = v.w;
    stq(w, a.q); stq(w + 1, b.q);
}
__device__ __forceinline__ float4 unp(u64 lo, u64 hi) {
    union { u64 q; float f[2]; } a, b; a.q = lo; b.q = hi;
    return make_float4(a.f[0], a.f[1], b.f[0], b.f[1]);
}
// H layout: u64 H[NSLOT][NBLK][4][128]; rows: 0=v0 last, 1=v0 first, 2=v1 first, 3=x first
__device__ __forceinline__ u64* recq(u64* H, int slot, int blk, int row) {
    return H + ((((size_t)slot * NBLK + blk) * 4 + row) << 7);
}

__global__ void init_ws(u64* H, u64* parts) {
    int i = blockIdx.x * 256 + threadIdx.x;
    if (i < NSLOT * NBLK * 4 * 128) H[i] = SENT;
    if (i < KSTEPS * PWRD) parts[i] = SENT;
}

__global__ void __launch_bounds__(256) cp_persist(
    const float* __restrict__ y, const float* __restrict__ lambd,
    float* __restrict__ xout, float* __restrict__ xtout, float* __restrict__ uout,
    u64* __restrict__ H, u64* __restrict__ parts)
{
    __shared__ float sxt[9 * 256];
    __shared__ float sv0[8 * 256];
    const int tid = threadIdx.x;
    const int blk = blockIdx.x;
    const int bc = blk >> 5;           // image index [0,6)
    const int tile = blk & 31;         // [0,32)
    const int r0 = tile * R;
    const int c4 = tid & 63;
    const int trow = tid >> 6;         // [0,4)
    const int b = (bc >= Cc) ? 1 : 0;

    const float lamb = expf(lambd[0]);

    float4 yv[2], xreg[2], v0[2], v1[2], u0[2], u1[2], xtp[2];
    float4 yhalo = mk4(0.f, 0.f, 0.f, 0.f);
    if (trow == 0 && tile < 31) yhalo = ld4(y, bc * 16384 + (r0 + 8) * 64 + c4);

    // ---------------- init (step 0): x=y, v = nabla(y); publish halos + per-wave norm ----------------
    {
        float pa0 = 0.f, pa1 = 0.f;
        #pragma unroll
        for (int k = 0; k < 2; ++k) {
            const int rr = trow + 4 * k;
            const int gh = r0 + rr;
            const int j4 = bc * 16384 + gh * 64 + c4;
            yv[k] = ld4(y, j4);
            xreg[k] = yv[k];
            float4 dh = mk4(0.f, 0.f, 0.f, 0.f);
            if (gh < Hh - 1) {
                float4 yn = ld4(y, j4 + 64);
                dh.x = yn.x - yv[k].x; dh.y = yn.y - yv[k].y;
                dh.z = yn.z - yv[k].z; dh.w = yn.w - yv[k].w;
            }
            float4 dw;
            dw.x = yv[k].y - yv[k].x; dw.y = yv[k].z - yv[k].y; dw.z = yv[k].w - yv[k].z;
            float ynx = __shfl_down(yv[k].x, 1, 64);
            dw.w = (c4 < 63) ? (ynx - yv[k].w) : 0.f;
            v0[k] = dh; v1[k] = dw;
            ((float4*)(sv0 + rr * 256))[c4] = dh;
            pa0 += dh.x*dh.x + dh.y*dh.y + dh.z*dh.z + dh.w*dh.w;
            pa1 += dw.x*dw.x + dw.y*dw.y + dw.z*dw.z + dw.w*dw.w;
        }
        if (trow == 0) {
            pub4(recq(H, 0, blk, 1) + 2 * c4, v0[0]);
            pub4(recq(H, 0, blk, 2) + 2 * c4, v1[0]);
            pub4(recq(H, 0, blk, 3) + 2 * c4, xreg[0]);
        }
        if (trow == 3) pub4(recq(H, 0, blk, 0) + 2 * c4, v0[1]);   // row r0+7
        #pragma unroll
        for (int m = 1; m < 64; m <<= 1) {
            pa0 += __shfl_xor(pa0, m, 64);
            pa1 += __shfl_xor(pa1, m, 64);
        }
        asm volatile("s_waitcnt lgkmcnt(0)" ::: "memory");  // LDS state visible before token
        if (c4 == 0) {
            union { float f[2]; u64 q; } pk;
            pk.f[0] = pa0; pk.f[1] = pa1;
            stq(parts + blk * 4 + trow, pk.q);
        }
    }

    float sigma = 0.20412414523193150818f;   // 0.5/sqrt(6)
    float tau   = sigma;

    for (int s = 1; s <= KSTEPS; ++s) {
        const int p = (s - 1) % NSLOT;
        const u64* pb = parts + (size_t)(s - 1) * PWRD + c4 * 12;
        u64 t0, t1, t2, t3, t4, t5, t6, t7, t8, t9, ta, tb;
        float4 vmtop = mk4(0.f, 0.f, 0.f, 0.f);
        float4 v0h = vmtop, v1h = vmtop, xoh = vmtop;

        // ------- poll: 12 per-wave norm words/lane (+ own halo words for wave 0) -------
        if (trow == 0) {
            const u64* rm = recq(H, p, blk - 1, 0) + 2 * c4;   // valid only if tile>0
            const u64* r1 = recq(H, p, blk + 1, 1) + 2 * c4;   // valid only if tile<31
            const u64* r2 = recq(H, p, blk + 1, 2) + 2 * c4;
            const u64* r3 = recq(H, p, blk + 1, 3) + 2 * c4;
            u64 m0 = SENT, m1 = SENT, h0 = SENT, h1 = SENT, h2 = SENT, h3 = SENT, h4 = SENT, h5 = SENT;
            for (;;) {
                t0 = ldq(pb + 0);  t1 = ldq(pb + 1);  t2 = ldq(pb + 2);  t3 = ldq(pb + 3);
                t4 = ldq(pb + 4);  t5 = ldq(pb + 5);  t6 = ldq(pb + 6);  t7 = ldq(pb + 7);
                t8 = ldq(pb + 8);  t9 = ldq(pb + 9);  ta = ldq(pb + 10); tb = ldq(pb + 11);
                bool ok = (t0 != SENT) & (t1 != SENT) & (t2 != SENT) & (t3 != SENT)
                        & (t4 != SENT) & (t5 != SENT) & (t6 != SENT) & (t7 != SENT)
                        & (t8 != SENT) & (t9 != SENT) & (ta != SENT) & (tb != SENT);
                if (tile > 0) {
                    m0 = ldq(rm); m1 = ldq(rm + 1);
                    ok = ok & (m0 != SENT) & (m1 != SENT);
                }
                if (tile < 31) {
                    h0 = ldq(r1); h1 = ldq(r1 + 1);
                    h2 = ldq(r2); h3 = ldq(r2 + 1);
                    h4 = ldq(r3); h5 = ldq(r3 + 1);
                    ok = ok & (h0 != SENT) & (h1 != SENT) & (h2 != SENT)
                            & (h3 != SENT) & (h4 != SENT) & (h5 != SENT);
                }
                if (__all(ok)) break;
                __builtin_amdgcn_s_sleep(1);
            }
            if (tile > 0)  vmtop = unp(m0, m1);
            if (tile < 31) { v0h = unp(h0, h1); v1h = unp(h2, h3); xoh = unp(h4, h5); }
        } else {
            for (;;) {
                t0 = ldq(pb + 0);  t1 = ldq(pb + 1);  t2 = ldq(pb + 2);  t3 = ldq(pb + 3);
                t4 = ldq(pb + 4);  t5 = ldq(pb + 5);  t6 = ldq(pb + 6);  t7 = ldq(pb + 7);
                t8 = ldq(pb + 8);  t9 = ldq(pb + 9);  ta = ldq(pb + 10); tb = ldq(pb + 11);
                bool ok = (t0 != SENT) & (t1 != SENT) & (t2 != SENT) & (t3 != SENT)
                        & (t4 != SENT) & (t5 != SENT) & (t6 != SENT) & (t7 != SENT)
                        & (t8 != SENT) & (t9 != SENT) & (ta != SENT) & (tb != SENT);
                if (__all(ok)) break;
                __builtin_amdgcn_s_sleep(1);
            }
        }
        asm volatile("" ::: "memory");

        // ------- resets: publishers reset their own future-publish words (slot s+1, dead) -------
        if (s < KSTEPS) {
            u64* rb = recq(H, (s + 1) % NSLOT, blk, 0);
            if (trow == 0) {
                #pragma unroll
                for (int r = 1; r < 4; ++r) {
                    stq(rb + (r << 7) + 2 * c4, SENT);
                    stq(rb + (r << 7) + 2 * c4 + 1, SENT);
                }
            } else if (trow == 3) {
                stq(rb + 2 * c4, SENT);
                stq(rb + 2 * c4 + 1, SENT);
            }
        }

        // ------- group sums from polled words (fixed lane order + butterfly; deterministic) -------
        float g0 = 0.f, g1 = 0.f, g2 = 0.f, g3 = 0.f;
        {
            const u64 tt[12] = { t0, t1, t2, t3, t4, t5, t6, t7, t8, t9, ta, tb };
            float q0 = 0.f, q1 = 0.f;
            #pragma unroll
            for (int i = 0; i < 12; ++i) {
                union { u64 q; float f[2]; } a; a.q = tt[i];
                q0 += a.f[0]; q1 += a.f[1];
            }
            if (c4 < 32) { g0 = q0; g1 = q1; }   // lanes 0-31 polled blocks 0..95  (b=0)
            else         { g2 = q0; g3 = q1; }   // lanes 32-63 polled blocks 96..191 (b=1)
            #pragma unroll
            for (int m = 1; m < 64; m <<= 1) {
                g0 += __shfl_xor(g0, m, 64);
                g1 += __shfl_xor(g1, m, 64);
                g2 += __shfl_xor(g2, m, 64);
                g3 += __shfl_xor(g3, m, 64);
            }
        }
        const float s0 = lamb / fmaxf(sqrtf(b ? g2 : g0), lamb);
        const float s1 = lamb / fmaxf(sqrtf(b ? g3 : g1), lamb);
        const float chi = 1.0f / sqrtf(1.0f + tau);
        const float inv = 1.0f / (1.0f + tau);
        const float opc = 1.0f + chi;
        const int q = s % NSLOT;

        // ---------------- phase B (step s-1) ----------------
        #pragma unroll
        for (int k = 0; k < 2; ++k) {
            const int rr = trow + 4 * k;
            const int gh = r0 + rr;
            float4 uu0, uu1;
            uu0.x = v0[k].x*s0; uu0.y = v0[k].y*s0; uu0.z = v0[k].z*s0; uu0.w = v0[k].w*s0;
            uu1.x = v1[k].x*s1; uu1.y = v1[k].y*s1; uu1.z = v1[k].z*s1; uu1.w = v1[k].w*s1;
            float4 vm = (k == 0) ? ((trow > 0) ? ((float4*)(sv0 + (trow - 1) * 256))[c4] : vmtop)
                                 : ((float4*)(sv0 + (trow + 3) * 256))[c4];
            float nt0 = 0.f, nt1 = 0.f, nt2 = 0.f, nt3 = 0.f;
            if (gh > 0) { nt0 += vm.x*s0; nt1 += vm.y*s0; nt2 += vm.z*s0; nt3 += vm.w*s0; }
            if (gh < Hh - 1) { nt0 -= uu0.x; nt1 -= uu0.y; nt2 -= uu0.z; nt3 -= uu0.w; }
            float ul = __shfl_up(uu1.w, 1, 64);
            if (c4 > 0) nt0 += ul;
            nt1 += uu1.x; nt2 += uu1.y; nt3 += uu1.z;
            nt0 -= uu1.x; nt1 -= uu1.y; nt2 -= uu1.z;
            if (c4 < 63) nt3 -= uu1.w;
            float4 xp;
            xp.x = (xreg[k].x + tau * (yv[k].x - nt0)) * inv;
            xp.y = (xreg[k].y + tau * (yv[k].y - nt1)) * inv;
            xp.z = (xreg[k].z + tau * (yv[k].z - nt2)) * inv;
            xp.w = (xreg[k].w + tau * (yv[k].w - nt3)) * inv;
            xtp[k].x = opc * xp.x - chi * xreg[k].x;
            xtp[k].y = opc * xp.y - chi * xreg[k].y;
            xtp[k].z = opc * xp.z - chi * xreg[k].z;
            xtp[k].w = opc * xp.w - chi * xreg[k].w;
            u0[k] = uu0; u1[k] = uu1;
            if (s == KSTEPS) {
                const int j4 = bc * 16384 + gh * 64 + c4;
                const int iv4 = bc * 32768 + gh * 64 + c4;
                st4(xout, j4, xp);
                st4(xtout, j4, xtp[k]);
                st4(uout, iv4, uu0);
                st4(uout, iv4 + 16384, uu1);
            } else {
                xreg[k] = xp;
                if (rr >= 1) ((float4*)(sxt + rr * 256))[c4] = xtp[k];
                if (trow == 0 && k == 0) pub4(recq(H, q, blk, 3) + 2 * c4, xp);
            }
        }
        if (s == KSTEPS) break;

        // ---- redundant halo row r0+8 (wave 0, tile<31; always interior in h) ----
        if (trow == 0 && tile < 31) {
            float4 h0, h1;
            h0.x = v0h.x*s0; h0.y = v0h.y*s0; h0.z = v0h.z*s0; h0.w = v0h.w*s0;
            h1.x = v1h.x*s1; h1.y = v1h.y*s1; h1.z = v1h.z*s1; h1.w = v1h.w*s1;
            float4 vmh = ((float4*)(sv0 + 7 * 256))[c4];
            float nt0 = vmh.x*s0 - h0.x, nt1 = vmh.y*s0 - h0.y,
                  nt2 = vmh.z*s0 - h0.z, nt3 = vmh.w*s0 - h0.w;
            float hul = __shfl_up(h1.w, 1, 64);
            if (c4 > 0) nt0 += hul;
            nt1 += h1.x; nt2 += h1.y; nt3 += h1.z;
            nt0 -= h1.x; nt1 -= h1.y; nt2 -= h1.z;
            if (c4 < 63) nt3 -= h1.w;
            float4 xph, xth;
            xph.x = (xoh.x + tau * (yhalo.x - nt0)) * inv;
            xph.y = (xoh.y + tau * (yhalo.y - nt1)) * inv;
            xph.z = (xoh.z + tau * (yhalo.z - nt2)) * inv;
            xph.w = (xoh.w + tau * (yhalo.w - nt3)) * inv;
            xth.x = opc * xph.x - chi * xoh.x;
            xth.y = opc * xph.y - chi * xoh.y;
            xth.z = opc * xph.z - chi * xoh.z;
            xth.w = opc * xph.w - chi * xoh.w;
            ((float4*)(sxt + 8 * 256))[c4] = xth;
        }

        // ---- LDS-only barrier: order sxt/sv0 across waves WITHOUT draining vmcnt ----
        asm volatile("s_waitcnt lgkmcnt(0)" ::: "memory");
        __builtin_amdgcn_sched_barrier(0);
        __builtin_amdgcn_s_barrier();
        __builtin_amdgcn_sched_barrier(0);

        // ---------------- phase A (step s) ----------------
        const float sigs = sigma / chi;
        float pa0 = 0.f, pa1 = 0.f;
        #pragma unroll
        for (int k = 0; k < 2; ++k) {
            const int rr = trow + 4 * k;
            const int gh = r0 + rr;
            float4 dh = mk4(0.f, 0.f, 0.f, 0.f);
            if (gh < Hh - 1) {
                float4 xn = ((const float4*)(sxt + (rr + 1) * 256))[c4];
                dh.x = xn.x - xtp[k].x; dh.y = xn.y - xtp[k].y;
                dh.z = xn.z - xtp[k].z; dh.w = xn.w - xtp[k].w;
            }
            float4 dw;
            dw.x = xtp[k].y - xtp[k].x; dw.y = xtp[k].z - xtp[k].y; dw.z = xtp[k].w - xtp[k].z;
            float xnx = __shfl_down(xtp[k].x, 1, 64);
            dw.w = (c4 < 63) ? (xnx - xtp[k].w) : 0.f;
            v0[k].x = fmaf(sigs, dh.x, u0[k].x); v0[k].y = fmaf(sigs, dh.y, u0[k].y);
            v0[k].z = fmaf(sigs, dh.z, u0[k].z); v0[k].w = fmaf(sigs, dh.w, u0[k].w);
            v1[k].x = fmaf(sigs, dw.x, u1[k].x); v1[k].y = fmaf(sigs, dw.y, u1[k].y);
            v1[k].z = fmaf(sigs, dw.z, u1[k].z); v1[k].w = fmaf(sigs, dw.w, u1[k].w);
            ((float4*)(sv0 + rr * 256))[c4] = v0[k];
            pa0 += v0[k].x*v0[k].x + v0[k].y*v0[k].y + v0[k].z*v0[k].z + v0[k].w*v0[k].w;
            pa1 += v1[k].x*v1[k].x + v1[k].y*v1[k].y + v1[k].z*v1[k].z + v1[k].w*v1[k].w;
            if (trow == 0 && k == 0) {
                pub4(recq(H, q, blk, 1) + 2 * c4, v0[0]);
                pub4(recq(H, q, blk, 2) + 2 * c4, v1[0]);
            }
            if (trow == 3 && k == 1) pub4(recq(H, q, blk, 0) + 2 * c4, v0[1]);
        }
        #pragma unroll
        for (int m = 1; m < 64; m <<= 1) {
            pa0 += __shfl_xor(pa0, m, 64);
            pa1 += __shfl_xor(pa1, m, 64);
        }
        asm volatile("s_waitcnt lgkmcnt(0)" ::: "memory");  // own LDS writes done before token
        if (c4 == 0) {
            union { float f[2]; u64 q; } pk;
            pk.f[0] = pa0; pk.f[1] = pa1;
            stq(parts + (size_t)s * PWRD + blk * 4 + trow, pk.q);
        }

        tau *= chi;
        sigma = sigs;
    }
}

extern "C" void kernel_launch(void* const* d_in, const int* in_sizes, int n_in,
                              void* d_out, int out_size, void* d_ws, size_t ws_size,
                              hipStream_t stream) {
    (void)in_sizes; (void)n_in; (void)out_size; (void)ws_size;
    const float* y     = (const float*)d_in[0];
    const float* lambd = (const float*)d_in[1];
    float* xout  = (float*)d_out;       // [0, NX)
    float* xtout = xout + NX;           // [NX, 2NX)
    float* uout  = xout + 2 * NX;       // [2NX, 2NX+NU)

    u64* H     = (u64*)d_ws;                         // [NSLOT][NBLK][4][128]
    u64* parts = H + (size_t)NSLOT * NBLK * 4 * 128; // [KSTEPS][NBLK][4]

    init_ws<<<(NSLOT * NBLK * 4 * 128 + 255) / 256, 256, 0, stream>>>(H, parts);
    cp_persist<<<NBLK, 256, 0, stream>>>(y, lambd, xout, xtout, uout, H, parts);
}

// Round 11
// 211.412 us; speedup vs baseline: 4.9129x; 2.2813x over previous
//
#include <hip/hip_runtime.h>
#include <math.h>

constexpr int Cc = 3, Hh = 256;
constexpr int NX = 393216;                 // 2*3*256*256
constexpr int R = 8;                       // rows per block
constexpr int NBLK = 192;                  // 6 images * 32 tiles (1 block/CU)
constexpr int KSTEPS = 50;
constexpr int ROWQ = 128;                  // u64 per halo row (256 floats)
constexpr int BROWS = 12;                  // halo rows per block per slot
constexpr int SLOTQ = NBLK * BROWS * ROWQ; // 294912 u64 per slot
constexpr int PW = NBLK * 4;               // per-step parts words (per wave)

using u64 = unsigned long long;
constexpr u64 SENT = 0x8000000080000000ull;  // (-0.0f,-0.0f): unreachable payload

__device__ __forceinline__ float4 ld4(const float* p, int i) { return ((const float4*)p)[i]; }
__device__ __forceinline__ void st4(float* p, int i, float4 v) { ((float4*)p)[i] = v; }
__device__ __forceinline__ float4 mk4(float a, float b, float c, float d) { return make_float4(a, b, c, d); }
__device__ __forceinline__ u64 ldq(const u64* p) {
    return __hip_atomic_load(p, __ATOMIC_RELAXED, __HIP_MEMORY_SCOPE_AGENT);
}
__device__ __forceinline__ void stq(u64* p, u64 v) {
    __hip_atomic_store(p, v, __ATOMIC_RELAXED, __HIP_MEMORY_SCOPE_AGENT);
}
__device__ __forceinline__ void pub4(u64* w, float4 v) {
    union { float f[2]; u64 q; } a, b;
    a.f[0] = v.x; a.f[1] = v.y; b.f[0] = v.z; b.f[1] = v.w;
    stq(w, a.q); stq(w + 1, b.q);
}
__device__ __forceinline__ float4 unp(u64 lo, u64 hi) {
    union { u64 q; float f[2]; } a, b; a.q = lo; b.q = hi;
    return make_float4(a.f[0], a.f[1], b.f[0], b.f[1]);
}
// field = P + a*A + b*B  (shared by owner and halo-recompute: bit-exact)
__device__ __forceinline__ float4 col3(float4 P, float4 A, float4 B, float a, float b) {
    return mk4(fmaf(a, A.x, fmaf(b, B.x, P.x)), fmaf(a, A.y, fmaf(b, B.y, P.y)),
               fmaf(a, A.z, fmaf(b, B.z, P.z)), fmaf(a, A.w, fmaf(b, B.w, P.w)));
}
__device__ __forceinline__ float4 f4sub(float4 a, float4 b) {
    return mk4(a.x - b.x, a.y - b.y, a.z - b.z, a.w - b.w);
}
__device__ __forceinline__ float4 f4s(float4 a, float s) {
    return mk4(a.x * s, a.y * s, a.z * s, a.w * s);
}
__device__ __forceinline__ float4 f4fma(float s, float4 a, float4 b) {   // s*a + b
    return mk4(fmaf(s, a.x, b.x), fmaf(s, a.y, b.y), fmaf(s, a.z, b.z), fmaf(s, a.w, b.w));
}
// NT0 (h-direction unit-contribution): +vm(if up) - v0(if dn)
__device__ __forceinline__ float4 nth(float4 vm, bool up, float4 v0x, bool dn) {
    return mk4((up ? vm.x : 0.f) - (dn ? v0x.x : 0.f), (up ? vm.y : 0.f) - (dn ? v0x.y : 0.f),
               (up ? vm.z : 0.f) - (dn ? v0x.z : 0.f), (up ? vm.w : 0.f) - (dn ? v0x.w : 0.f));
}
// NT1 (w-direction unit-contribution)
__device__ __forceinline__ float4 ntw(float4 v1x, int c4) {
    float ul = __shfl_up(v1x.w, 1, 64);
    return mk4(((c4 > 0) ? ul : 0.f) - v1x.x, v1x.x - v1x.y, v1x.y - v1x.z,
               v1x.z - ((c4 < 63) ? v1x.w : 0.f));
}
// w-gradient of a register row
__device__ __forceinline__ float4 gradw(float4 t, int c4) {
    float xn = __shfl_down(t.x, 1, 64);
    return mk4(t.y - t.x, t.z - t.y, t.w - t.z, (c4 < 63) ? (xn - t.w) : 0.f);
}
__device__ __forceinline__ void barld() {
    asm volatile("s_waitcnt lgkmcnt(0)" ::: "memory");
    __builtin_amdgcn_sched_barrier(0);
    __builtin_amdgcn_s_barrier();
    __builtin_amdgcn_sched_barrier(0);
}

__global__ void init_ws(u64* h0, u64* h1, u64* h2, u64* parts) {
    int i = blockIdx.x * 256 + threadIdx.x;
    if (i < SLOTQ) { h0[i] = SENT; h1[i] = SENT; h2[i] = SENT; }
    if (i < (KSTEPS + 1) * PW) parts[i] = SENT;
}

__global__ void __launch_bounds__(256, 1) cp_persist(
    const float* __restrict__ y, const float* __restrict__ lambd,
    float* __restrict__ xout, float* __restrict__ xtout, float* __restrict__ uout,
    u64* __restrict__ h0, u64* __restrict__ h1, u64* __restrict__ h2,
    u64* __restrict__ parts)
{
    __shared__ float sv0[8 * 256];
    __shared__ float sxtP[9 * 256];
    __shared__ float sxtA[9 * 256];
    __shared__ float sxtB[9 * 256];

    const int tid = threadIdx.x, blk = blockIdx.x;
    const int bc = blk >> 5, tile = blk & 31, r0 = tile * R;
    const int c4 = tid & 63, trow = tid >> 6;
    const int b = (bc >= Cc) ? 1 : 0;
    const float lamb = expf(lambd[0]);

    float4 yv[2], xcur[2], v0c[2], v1c[2];
    float4 xpP[2], xpA[2], xpB[2];
    float4 p0P[2], p0A[2], p0B[2], p1P[2], p1A[2], p1B[2];
    float4 yh = mk4(0, 0, 0, 0), vmtop = yh, v0h = yh, v1h = yh, xoh = yh;

    float tau = 0.20412414523193150818f;   // tau_0 = sigma_0 = 0.5/sqrt(6)
    float sig = tau;
    float chi = 0.f, sigs = 0.f;
    float alpha = 0.f, beta = 0.f;

    auto slotp = [&](int r) -> u64* { return (r == 0) ? h0 : ((r == 1) ? h1 : h2); };

    auto wavesum2 = [&](float& a, float& bb) {
        #pragma unroll
        for (int m = 1; m < 64; m <<= 1) { a += __shfl_xor(a, m, 64); bb += __shfl_xor(bb, m, 64); }
    };

    // poll parts[s] for our batch (384 words, 6/lane) -> alpha,beta (deterministic fixed-order sum)
    auto pollscale = [&](int s) {
        const u64* pb = parts + (size_t)s * PW + b * (PW / 2) + c4 * 6;
        u64 q0, q1, q2, q3, q4, q5;
        for (;;) {
            q0 = ldq(pb); q1 = ldq(pb + 1); q2 = ldq(pb + 2);
            q3 = ldq(pb + 3); q4 = ldq(pb + 4); q5 = ldq(pb + 5);
            bool ok = (q0 != SENT) && (q1 != SENT) && (q2 != SENT) &&
                      (q3 != SENT) && (q4 != SENT) && (q5 != SENT);
            if (__all(ok)) break;
            __builtin_amdgcn_s_sleep(1);
        }
        asm volatile("" ::: "memory");
        float g0 = 0.f, g1 = 0.f;
        union { u64 q; float f[2]; } u_;
        u_.q = q0; g0 += u_.f[0]; g1 += u_.f[1];
        u_.q = q1; g0 += u_.f[0]; g1 += u_.f[1];
        u_.q = q2; g0 += u_.f[0]; g1 += u_.f[1];
        u_.q = q3; g0 += u_.f[0]; g1 += u_.f[1];
        u_.q = q4; g0 += u_.f[0]; g1 += u_.f[1];
        u_.q = q5; g0 += u_.f[0]; g1 += u_.f[1];
        wavesum2(g0, g1);
        alpha = lamb / fmaxf(sqrtf(g0), lamb);
        beta  = lamb / fmaxf(sqrtf(g1), lamb);
    };

    auto pubparts = [&](int s) {
        float pa0 = 0.f, pa1 = 0.f;
        #pragma unroll
        for (int k = 0; k < 2; ++k) {
            pa0 += v0c[k].x * v0c[k].x + v0c[k].y * v0c[k].y + v0c[k].z * v0c[k].z + v0c[k].w * v0c[k].w;
            pa1 += v1c[k].x * v1c[k].x + v1c[k].y * v1c[k].y + v1c[k].z * v1c[k].z + v1c[k].w * v1c[k].w;
        }
        wavesum2(pa0, pa1);
        if (c4 == 0) {
            union { float f[2]; u64 q; } pk; pk.f[0] = pa0; pk.f[1] = pa1;
            stq(parts + (size_t)s * PW + blk * 4 + trow, pk.q);
        }
    };

    // expansion: from concrete (xcur, v0c, v1c, halos) produce P/A/B pieces of x_next and v_next
    auto expand = [&](u64* hb, bool pub) {
        const float inv = 1.f / (1.f + tau);
        const float tin = tau * inv;
        const float opc = 1.f + chi;
        float4 xtP[2], xtA[2], xtB[2];
        // ---- pass 1: NT decomposition, x pieces, xt pieces into LDS ----
        #pragma unroll
        for (int k = 0; k < 2; ++k) {
            const int rr = trow + 4 * k, gh = r0 + rr;
            float4 vm = (k == 0) ? ((trow > 0) ? ((float4*)(sv0 + (trow - 1) * 256))[c4] : vmtop)
                                 : ((float4*)(sv0 + (trow + 3) * 256))[c4];
            float4 NT0 = nth(vm, gh > 0, v0c[k], gh < Hh - 1);
            float4 NT1 = ntw(v1c[k], c4);
            float4 BASE = f4s(f4fma(tau, yv[k], xcur[k]), inv);
            float4 xA = f4s(NT0, -tin);
            float4 xB = f4s(NT1, -tin);
            xpP[k] = BASE; xpA[k] = xA; xpB[k] = xB;
            xtP[k] = f4fma(-chi, xcur[k], f4s(BASE, opc));
            xtA[k] = f4s(xA, opc);
            xtB[k] = f4s(xB, opc);
            if (rr >= 1) {
                ((float4*)(sxtP + rr * 256))[c4] = xtP[k];
                ((float4*)(sxtA + rr * 256))[c4] = xtA[k];
                ((float4*)(sxtB + rr * 256))[c4] = xtB[k];
            }
            if (pub && trow == 0 && k == 0) {
                u64* rbase = hb + ((size_t)blk * BROWS) * ROWQ;
                pub4(rbase +  9 * ROWQ + 2 * c4, BASE);
                pub4(rbase + 10 * ROWQ + 2 * c4, xA);
                pub4(rbase + 11 * ROWQ + 2 * c4, xB);
            }
        }
        // ---- halo row r0+8 recompute (wave 0, tile<31): identical helpers -> bit-exact ----
        if (trow == 0 && tile < 31) {
            float4 vmh = ((float4*)(sv0 + 7 * 256))[c4];
            float4 NT0h = nth(vmh, true, v0h, true);     // gh2 in [8,248]: interior
            float4 NT1h = ntw(v1h, c4);
            float4 BASEh = f4s(f4fma(tau, yh, xoh), inv);
            float4 xAh = f4s(NT0h, -tin);
            float4 xBh = f4s(NT1h, -tin);
            ((float4*)(sxtP + 8 * 256))[c4] = f4fma(-chi, xoh, f4s(BASEh, opc));
            ((float4*)(sxtA + 8 * 256))[c4] = f4s(xAh, opc);
            ((float4*)(sxtB + 8 * 256))[c4] = f4s(xBh, opc);
        }
        barld();   // B2: xt pieces visible
        // ---- pass 2: gradients -> v pieces ----
        #pragma unroll
        for (int k = 0; k < 2; ++k) {
            const int rr = trow + 4 * k, gh = r0 + rr;
            float4 dhP = mk4(0, 0, 0, 0), dhA = dhP, dhB = dhP;
            if (gh < Hh - 1) {
                dhP = f4sub(((float4*)(sxtP + (rr + 1) * 256))[c4], xtP[k]);
                dhA = f4sub(((float4*)(sxtA + (rr + 1) * 256))[c4], xtA[k]);
                dhB = f4sub(((float4*)(sxtB + (rr + 1) * 256))[c4], xtB[k]);
            }
            float4 dwP = gradw(xtP[k], c4);
            float4 dwA = gradw(xtA[k], c4);
            float4 dwB = gradw(xtB[k], c4);
            p0P[k] = f4s(dhP, sigs);
            p0A[k] = f4fma(sigs, dhA, v0c[k]);
            p0B[k] = f4s(dhB, sigs);
            p1P[k] = f4s(dwP, sigs);
            p1A[k] = f4s(dwA, sigs);
            p1B[k] = f4fma(sigs, dwB, v1c[k]);
            if (pub) {
                u64* rbase = hb + ((size_t)blk * BROWS) * ROWQ;
                if (trow == 0 && k == 0) {
                    pub4(rbase + 3 * ROWQ + 2 * c4, p0P[0]);
                    pub4(rbase + 4 * ROWQ + 2 * c4, p0A[0]);
                    pub4(rbase + 5 * ROWQ + 2 * c4, p0B[0]);
                    pub4(rbase + 6 * ROWQ + 2 * c4, p1P[0]);
                    pub4(rbase + 7 * ROWQ + 2 * c4, p1A[0]);
                    pub4(rbase + 8 * ROWQ + 2 * c4, p1B[0]);
                }
                if (trow == 3 && k == 1) {
                    pub4(rbase + 0 * ROWQ + 2 * c4, p0P[1]);
                    pub4(rbase + 1 * ROWQ + 2 * c4, p0A[1]);
                    pub4(rbase + 2 * ROWQ + 2 * c4, p0B[1]);
                }
            }
        }
        barld();   // B3: protects sxt/sv0 for next iteration
    };

    // ================= INIT (iteration 0) =================
    {
        #pragma unroll
        for (int k = 0; k < 2; ++k) {
            const int rr = trow + 4 * k, gh = r0 + rr;
            const int j4 = bc * 16384 + gh * 64 + c4;
            yv[k] = ld4(y, j4);
            xcur[k] = yv[k];
            float4 dh = mk4(0, 0, 0, 0);
            if (gh < Hh - 1) dh = f4sub(ld4(y, j4 + 64), yv[k]);
            float4 dw = gradw(yv[k], c4);
            v0c[k] = dh; v1c[k] = dw;
            ((float4*)(sv0 + rr * 256))[c4] = dh;
        }
        if (trow == 0) {
            if (tile < 31) {
                const int j4h = bc * 16384 + (r0 + 8) * 64 + c4;
                yh = ld4(y, j4h);
                v0h = f4sub(ld4(y, j4h + 64), yh);
                v1h = gradw(yh, c4);
                xoh = yh;
            }
            if (tile > 0) {
                float4 ym = ld4(y, bc * 16384 + (r0 - 1) * 64 + c4);
                vmtop = f4sub(yv[0], ym);     // v1^0 @ r0-1 = y[r0]-y[r0-1]
            }
        }
        pubparts(1);                           // n_1 = ||nabla y||^2 partials
        chi = 1.f / sqrtf(1.f + tau);
        sigs = sig / chi;                      // sigma_1
        barld();                               // B1: sv0 visible
        expand(slotp(0), true);                // pieces of x_1, v_2 -> slot 0
        tau *= chi; sig = sigs;
    }

    // ================= MAIN LOOP (s = 1..49) =================
    for (int s = 1; s < KSTEPS; ++s) {
        pollscale(s);                          // scales of step s (instant-hit in steady state)
        chi = 1.f / sqrtf(1.f + tau);
        sigs = sig / chi;

        // collapse own rows -> concrete x_s, v_{s+1}
        #pragma unroll
        for (int k = 0; k < 2; ++k) {
            xcur[k] = col3(xpP[k], xpA[k], xpB[k], alpha, beta);
            v0c[k]  = col3(p0P[k], p0A[k], p0B[k], alpha, beta);
            v1c[k]  = col3(p1P[k], p1A[k], p1B[k], alpha, beta);
            ((float4*)(sv0 + (trow + 4 * k) * 256))[c4] = v0c[k];
        }
        // halo poll + collapse (wave 0) from slot (s-1)%3
        u64* hbp = slotp((s - 1) % 3);
        if (trow == 0) {
            if (tile > 0) {
                const u64* ra = hbp + ((size_t)(blk - 1) * BROWS) * ROWQ + 2 * c4;
                u64 a0, a1, a2, a3, a4, a5;
                for (;;) {
                    a0 = ldq(ra);            a1 = ldq(ra + 1);
                    a2 = ldq(ra + ROWQ);     a3 = ldq(ra + ROWQ + 1);
                    a4 = ldq(ra + 2 * ROWQ); a5 = ldq(ra + 2 * ROWQ + 1);
                    if (__all((a0 != SENT) && (a1 != SENT) && (a2 != SENT) &&
                              (a3 != SENT) && (a4 != SENT) && (a5 != SENT))) break;
                    __builtin_amdgcn_s_sleep(1);
                }
                vmtop = col3(unp(a0, a1), unp(a2, a3), unp(a4, a5), alpha, beta);
            }
            if (tile < 31) {
                const u64* rb = hbp + ((size_t)(blk + 1) * BROWS) * ROWQ + 2 * c4;
                u64 b0, b1, b2, b3, b4, b5, b6, b7, b8, b9, b10, b11, b12, b13, b14, b15, b16, b17;
                for (;;) {
                    b0  = ldq(rb + 3 * ROWQ);  b1  = ldq(rb + 3 * ROWQ + 1);
                    b2  = ldq(rb + 4 * ROWQ);  b3  = ldq(rb + 4 * ROWQ + 1);
                    b4  = ldq(rb + 5 * ROWQ);  b5  = ldq(rb + 5 * ROWQ + 1);
                    b6  = ldq(rb + 6 * ROWQ);  b7  = ldq(rb + 6 * ROWQ + 1);
                    b8  = ldq(rb + 7 * ROWQ);  b9  = ldq(rb + 7 * ROWQ + 1);
                    b10 = ldq(rb + 8 * ROWQ);  b11 = ldq(rb + 8 * ROWQ + 1);
                    b12 = ldq(rb + 9 * ROWQ);  b13 = ldq(rb + 9 * ROWQ + 1);
                    b14 = ldq(rb + 10 * ROWQ); b15 = ldq(rb + 10 * ROWQ + 1);
                    b16 = ldq(rb + 11 * ROWQ); b17 = ldq(rb + 11 * ROWQ + 1);
                    bool ok = (b0 != SENT) && (b1 != SENT) && (b2 != SENT) && (b3 != SENT) &&
                              (b4 != SENT) && (b5 != SENT) && (b6 != SENT) && (b7 != SENT) &&
                              (b8 != SENT) && (b9 != SENT) && (b10 != SENT) && (b11 != SENT) &&
                              (b12 != SENT) && (b13 != SENT) && (b14 != SENT) && (b15 != SENT) &&
                              (b16 != SENT) && (b17 != SENT);
                    if (__all(ok)) break;
                    __builtin_amdgcn_s_sleep(1);
                }
                v0h = col3(unp(b0, b1),   unp(b2, b3),   unp(b4, b5),   alpha, beta);
                v1h = col3(unp(b6, b7),   unp(b8, b9),   unp(b10, b11), alpha, beta);
                xoh = col3(unp(b12, b13), unp(b14, b15), unp(b16, b17), alpha, beta);
            }
        }
        asm volatile("" ::: "memory");
        // resets of slot (s+1)%3 (holds step s-2 pieces; provably dead after pollscale(s))
        if (s <= 47) {
            u64* rb2 = slotp((s + 1) % 3) + ((size_t)blk * BROWS) * ROWQ;
            if (trow == 0) {
                #pragma unroll
                for (int r = 3; r < 12; ++r) {
                    stq(rb2 + r * ROWQ + 2 * c4, SENT);
                    stq(rb2 + r * ROWQ + 2 * c4 + 1, SENT);
                }
            } else if (trow == 3) {
                #pragma unroll
                for (int r = 0; r < 3; ++r) {
                    stq(rb2 + r * ROWQ + 2 * c4, SENT);
                    stq(rb2 + r * ROWQ + 2 * c4 + 1, SENT);
                }
            }
        }
        pubparts(s + 1);                       // ||v_{s+1}||^2 partials (early publish)
        barld();                               // B1: sv0 visible
        expand(slotp(s % 3), s < KSTEPS - 1);  // s=49: compute pieces, skip publishes
        tau *= chi; sig = sigs;
    }

    // ================= FINAL (step 50) =================
    pollscale(KSTEPS);                         // s_50 (gate: all blocks past their pieces-48 reads)
    const float opc = 1.f + chi;               // chi = chi_49
    #pragma unroll
    for (int k = 0; k < 2; ++k) {
        const int rr = trow + 4 * k, gh = r0 + rr;
        const int j4 = bc * 16384 + gh * 64 + c4;
        const int iv4 = bc * 32768 + gh * 64 + c4;
        float4 xf_ = col3(xpP[k], xpA[k], xpB[k], alpha, beta);        // x_50
        float4 xtf = f4fma(-chi, xcur[k], f4s(xf_, opc));              // xcur = x_49
        st4(xout, j4, xf_);
        st4(xtout, j4, xtf);
        st4(uout, iv4, f4s(v0c[k], alpha));                            // u_50 = s_50 * v_50
        st4(uout, iv4 + 16384, f4s(v1c[k], beta));
    }
}

extern "C" void kernel_launch(void* const* d_in, const int* in_sizes, int n_in,
                              void* d_out, int out_size, void* d_ws, size_t ws_size,
                              hipStream_t stream) {
    (void)in_sizes; (void)n_in; (void)out_size; (void)ws_size;
    const float* y     = (const float*)d_in[0];
    const float* lambd = (const float*)d_in[1];
    float* xout  = (float*)d_out;       // [0, NX)
    float* xtout = xout + NX;           // [NX, 2NX)
    float* uout  = xout + 2 * NX;       // [2NX, 2NX+NU)

    // piece slots 0,1 live in d_out (2*SLOTQ*8 = 4.72 MB <= 6.29 MB; consumed before
    // final output writes, gated by the parts[50] poll). slot 2 + parts in d_ws.
    u64* h0 = (u64*)d_out;
    u64* h1 = h0 + SLOTQ;
    u64* h2 = (u64*)d_ws;
    u64* parts = h2 + SLOTQ;            // [(KSTEPS+1)][NBLK][4] u64

    init_ws<<<SLOTQ / 256, 256, 0, stream>>>(h0, h1, h2, parts);
    cp_persist<<<NBLK, 256, 0, stream>>>(y, lambd, xout, xtout, uout, h0, h1, h2, parts);
}

// Round 12
// 208.454 us; speedup vs baseline: 4.9826x; 1.0142x over previous
//
#include <hip/hip_runtime.h>
#include <math.h>

constexpr int Cc = 3, Hh = 256;
constexpr int NX = 393216;                 // 2*3*256*256
constexpr int R = 8;                       // rows per block
constexpr int NBLK = 192;                  // 6 images * 32 tiles (1 block/CU)
constexpr int KSTEPS = 50;
constexpr int ROWQ = 128;                  // u64 per halo row (256 floats)
constexpr int BROWS = 12;                  // halo rows per block per slot
constexpr int SLOTQ = NBLK * BROWS * ROWQ; // 294912 u64 per slot

using u64 = unsigned long long;
constexpr u64 SENT = 0x8000000080000000ull;  // (-0.0f,-0.0f): unreachable payload

__device__ __forceinline__ float4 ld4(const float* p, int i) { return ((const float4*)p)[i]; }
__device__ __forceinline__ void st4(float* p, int i, float4 v) { ((float4*)p)[i] = v; }
__device__ __forceinline__ float4 mk4(float a, float b, float c, float d) { return make_float4(a, b, c, d); }
__device__ __forceinline__ u64 ldq(const u64* p) {
    return __hip_atomic_load(p, __ATOMIC_RELAXED, __HIP_MEMORY_SCOPE_AGENT);
}
__device__ __forceinline__ void stq(u64* p, u64 v) {
    __hip_atomic_store(p, v, __ATOMIC_RELAXED, __HIP_MEMORY_SCOPE_AGENT);
}
__device__ __forceinline__ void pub4(u64* w, float4 v) {
    union { float f[2]; u64 q; } a, b;
    a.f[0] = v.x; a.f[1] = v.y; b.f[0] = v.z; b.f[1] = v.w;
    stq(w, a.q); stq(w + 1, b.q);
}
__device__ __forceinline__ float4 unp(u64 lo, u64 hi) {
    union { u64 q; float f[2]; } a, b; a.q = lo; b.q = hi;
    return make_float4(a.f[0], a.f[1], b.f[0], b.f[1]);
}
// field = P + a*A + b*B  (shared by owner and halo-recompute: bit-exact)
__device__ __forceinline__ float4 col3(float4 P, float4 A, float4 B, float a, float b) {
    return mk4(fmaf(a, A.x, fmaf(b, B.x, P.x)), fmaf(a, A.y, fmaf(b, B.y, P.y)),
               fmaf(a, A.z, fmaf(b, B.z, P.z)), fmaf(a, A.w, fmaf(b, B.w, P.w)));
}
__device__ __forceinline__ float4 f4sub(float4 a, float4 b) {
    return mk4(a.x - b.x, a.y - b.y, a.z - b.z, a.w - b.w);
}
__device__ __forceinline__ float4 f4s(float4 a, float s) {
    return mk4(a.x * s, a.y * s, a.z * s, a.w * s);
}
__device__ __forceinline__ float4 f4fma(float s, float4 a, float4 b) {   // s*a + b
    return mk4(fmaf(s, a.x, b.x), fmaf(s, a.y, b.y), fmaf(s, a.z, b.z), fmaf(s, a.w, b.w));
}
// NT0 (h-direction unit-contribution): +vm(if up) - v0(if dn)
__device__ __forceinline__ float4 nth(float4 vm, bool up, float4 v0x, bool dn) {
    return mk4((up ? vm.x : 0.f) - (dn ? v0x.x : 0.f), (up ? vm.y : 0.f) - (dn ? v0x.y : 0.f),
               (up ? vm.z : 0.f) - (dn ? v0x.z : 0.f), (up ? vm.w : 0.f) - (dn ? v0x.w : 0.f));
}
// NT1 (w-direction unit-contribution)
__device__ __forceinline__ float4 ntw(float4 v1x, int c4) {
    float ul = __shfl_up(v1x.w, 1, 64);
    return mk4(((c4 > 0) ? ul : 0.f) - v1x.x, v1x.x - v1x.y, v1x.y - v1x.z,
               v1x.z - ((c4 < 63) ? v1x.w : 0.f));
}
// w-gradient of a register row
__device__ __forceinline__ float4 gradw(float4 t, int c4) {
    float xn = __shfl_down(t.x, 1, 64);
    return mk4(t.y - t.x, t.z - t.y, t.w - t.z, (c4 < 63) ? (xn - t.w) : 0.f);
}
__device__ __forceinline__ void barld() {
    asm volatile("s_waitcnt lgkmcnt(0)" ::: "memory");
    __builtin_amdgcn_sched_barrier(0);
    __builtin_amdgcn_s_barrier();
    __builtin_amdgcn_sched_barrier(0);
}

__global__ void init_ws(u64* h0, u64* h1, u64* h2, u64* parts) {
    int i = blockIdx.x * 256 + threadIdx.x;
    if (i < SLOTQ) { h0[i] = SENT; h1[i] = SENT; h2[i] = SENT; }
    if (i < (KSTEPS + 1) * NBLK) parts[i] = SENT;
}

__global__ void __launch_bounds__(512, 1) cp_persist(
    const float* __restrict__ y, const float* __restrict__ lambd,
    float* __restrict__ xout, float* __restrict__ xtout, float* __restrict__ uout,
    u64* __restrict__ h0, u64* __restrict__ h1, u64* __restrict__ h2,
    u64* __restrict__ parts)
{
    __shared__ float sv0[8 * 256];
    __shared__ float sxtP[9 * 256];
    __shared__ float sxtA[9 * 256];
    __shared__ float sxtB[9 * 256];
    __shared__ float2 pw[8];

    const int tid = threadIdx.x, blk = blockIdx.x;
    const int bc = blk >> 5, tile = blk & 31, r0 = tile * R;
    const int c4 = tid & 63, trow = tid >> 6;    // trow in [0,8): one row per wave
    const int b = (bc >= Cc) ? 1 : 0;
    const float lamb = expf(lambd[0]);
    const int gh = r0 + trow;
    const int j4 = bc * 16384 + gh * 64 + c4;

    float4 yv, xcur, v0c, v1c;
    float4 xpP, xpA, xpB, p0P, p0A, p0B, p1P, p1A, p1B;
    float4 yh = mk4(0, 0, 0, 0), vmtop = yh, v0h = yh, v1h = yh, xoh = yh;

    float tau = 0.20412414523193150818f;   // tau_0 = sigma_0 = 0.5/sqrt(6)
    float sig = tau;
    float chi = 0.f, sigs = 0.f;
    float alpha = 0.f, beta = 0.f;

    auto slotp = [&](int r) -> u64* { return (r == 0) ? h0 : ((r == 1) ? h1 : h2); };

    auto wavesum2 = [&](float& a, float& bb) {
        #pragma unroll
        for (int m = 1; m < 64; m <<= 1) { a += __shfl_xor(a, m, 64); bb += __shfl_xor(bb, m, 64); }
    };

    // poll parts[s] for our batch (96 words, 2/lane) -> alpha,beta (fixed-order, deterministic)
    auto pollscale = [&](int s) {
        const u64* pb = parts + (size_t)s * NBLK + b * 96;
        const int i1 = 64 + (c4 & 31);
        u64 q0, q1;
        for (;;) {
            q0 = ldq(pb + c4);
            q1 = ldq(pb + i1);
            if (__all((q0 != SENT) && (q1 != SENT))) break;
            __builtin_amdgcn_s_sleep(1);
        }
        asm volatile("" ::: "memory");
        union { u64 q; float f[2]; } a;
        a.q = q0;
        float g0 = a.f[0], g1 = a.f[1];
        a.q = q1;
        if (c4 < 32) { g0 += a.f[0]; g1 += a.f[1]; }
        wavesum2(g0, g1);
        alpha = lamb / fmaxf(sqrtf(g0), lamb);
        beta  = lamb / fmaxf(sqrtf(g1), lamb);
    };

    // per-wave norm -> LDS (pre-B1)
    auto wavenorm = [&]() {
        float pa0 = v0c.x*v0c.x + v0c.y*v0c.y + v0c.z*v0c.z + v0c.w*v0c.w;
        float pa1 = v1c.x*v1c.x + v1c.y*v1c.y + v1c.z*v1c.z + v1c.w*v1c.w;
        wavesum2(pa0, pa1);
        if (c4 == 0) pw[trow] = make_float2(pa0, pa1);
    };
    // block-sum publish (post-B1; one u64 per block)
    auto pubparts = [&](int s) {
        if (tid == 0) {
            float q0 = 0.f, q1 = 0.f;
            #pragma unroll
            for (int w = 0; w < 8; ++w) { q0 += pw[w].x; q1 += pw[w].y; }
            union { float f[2]; u64 q; } pk; pk.f[0] = q0; pk.f[1] = q1;
            stq(parts + (size_t)s * NBLK + blk, pk.q);
        }
    };

    // expansion: from concrete (xcur, v0c, v1c, halos) produce P/A/B pieces of x_next, v_next
    auto expand = [&](u64* hb, bool pub) {
        const float inv = 1.f / (1.f + tau);
        const float tin = tau * inv;
        const float opc = 1.f + chi;
        float4 xtP, xtA, xtB;
        // ---- pass 1: NT decomposition, x pieces, xt pieces into LDS ----
        {
            float4 vm = (trow > 0) ? ((float4*)(sv0 + (trow - 1) * 256))[c4] : vmtop;
            float4 NT0 = nth(vm, gh > 0, v0c, gh < Hh - 1);
            float4 NT1 = ntw(v1c, c4);
            float4 BASE = f4s(f4fma(tau, yv, xcur), inv);
            float4 xA = f4s(NT0, -tin);
            float4 xB = f4s(NT1, -tin);
            xpP = BASE; xpA = xA; xpB = xB;
            xtP = f4fma(-chi, xcur, f4s(BASE, opc));
            xtA = f4s(xA, opc);
            xtB = f4s(xB, opc);
            if (trow >= 1) {
                ((float4*)(sxtP + trow * 256))[c4] = xtP;
                ((float4*)(sxtA + trow * 256))[c4] = xtA;
                ((float4*)(sxtB + trow * 256))[c4] = xtB;
            }
            if (pub && trow == 0) {
                u64* rbase = hb + ((size_t)blk * BROWS) * ROWQ;
                pub4(rbase +  9 * ROWQ + 2 * c4, BASE);
                pub4(rbase + 10 * ROWQ + 2 * c4, xA);
                pub4(rbase + 11 * ROWQ + 2 * c4, xB);
            }
        }
        // ---- halo row r0+8 recompute (wave 0, tile<31): identical helpers -> bit-exact ----
        if (trow == 0 && tile < 31) {
            float4 vmh = ((float4*)(sv0 + 7 * 256))[c4];
            float4 NT0h = nth(vmh, true, v0h, true);     // gh2 in [8,248]: interior
            float4 NT1h = ntw(v1h, c4);
            float4 BASEh = f4s(f4fma(tau, yh, xoh), inv);
            float4 xAh = f4s(NT0h, -tin);
            float4 xBh = f4s(NT1h, -tin);
            ((float4*)(sxtP + 8 * 256))[c4] = f4fma(-chi, xoh, f4s(BASEh, opc));
            ((float4*)(sxtA + 8 * 256))[c4] = f4s(xAh, opc);
            ((float4*)(sxtB + 8 * 256))[c4] = f4s(xBh, opc);
        }
        barld();   // B2: xt pieces visible
        // ---- pass 2: gradients -> v pieces ----
        {
            float4 dhP = mk4(0, 0, 0, 0), dhA = dhP, dhB = dhP;
            if (gh < Hh - 1) {
                dhP = f4sub(((float4*)(sxtP + (trow + 1) * 256))[c4], xtP);
                dhA = f4sub(((float4*)(sxtA + (trow + 1) * 256))[c4], xtA);
                dhB = f4sub(((float4*)(sxtB + (trow + 1) * 256))[c4], xtB);
            }
            float4 dwP = gradw(xtP, c4);
            float4 dwA = gradw(xtA, c4);
            float4 dwB = gradw(xtB, c4);
            p0P = f4s(dhP, sigs);
            p0A = f4fma(sigs, dhA, v0c);
            p0B = f4s(dhB, sigs);
            p1P = f4s(dwP, sigs);
            p1A = f4s(dwA, sigs);
            p1B = f4fma(sigs, dwB, v1c);
            if (pub) {
                u64* rbase = hb + ((size_t)blk * BROWS) * ROWQ;
                if (trow == 0) {
                    pub4(rbase + 3 * ROWQ + 2 * c4, p0P);
                    pub4(rbase + 4 * ROWQ + 2 * c4, p0A);
                    pub4(rbase + 5 * ROWQ + 2 * c4, p0B);
                    pub4(rbase + 6 * ROWQ + 2 * c4, p1P);
                    pub4(rbase + 7 * ROWQ + 2 * c4, p1A);
                    pub4(rbase + 8 * ROWQ + 2 * c4, p1B);
                }
                if (trow == 7) {
                    pub4(rbase + 0 * ROWQ + 2 * c4, p0P);
                    pub4(rbase + 1 * ROWQ + 2 * c4, p0A);
                    pub4(rbase + 2 * ROWQ + 2 * c4, p0B);
                }
            }
        }
        barld();   // B3: protects sxt/sv0 for next iteration
    };

    // ================= INIT (iteration 0) =================
    {
        yv = ld4(y, j4);
        xcur = yv;
        float4 dh = mk4(0, 0, 0, 0);
        if (gh < Hh - 1) dh = f4sub(ld4(y, j4 + 64), yv);
        v0c = dh;
        v1c = gradw(yv, c4);
        ((float4*)(sv0 + trow * 256))[c4] = v0c;
        if (trow == 0) {
            if (tile < 31) {
                const int j4h = bc * 16384 + (r0 + 8) * 64 + c4;
                yh = ld4(y, j4h);
                v0h = f4sub(ld4(y, j4h + 64), yh);
                v1h = gradw(yh, c4);
                xoh = yh;
            }
            if (tile > 0) {
                float4 ym = ld4(y, bc * 16384 + (r0 - 1) * 64 + c4);
                vmtop = f4sub(yv, ym);     // v0^1 @ r0-1 = y[r0]-y[r0-1]
            }
        }
        wavenorm();                            // n_1 partial = ||nabla y||^2 (this block)
        barld();                               // B1: sv0 + pw visible
        pubparts(1);
        chi = 1.f / sqrtf(1.f + tau);
        sigs = sig / chi;                      // sigma_1
        expand(slotp(0), true);                // pieces of x_1, v_2 -> slot 0
        tau *= chi; sig = sigs;
    }

    // ================= MAIN LOOP (s = 1..49) =================
    for (int s = 1; s < KSTEPS; ++s) {
        pollscale(s);                          // scales of step s (instant-hit in steady state)
        chi = 1.f / sqrtf(1.f + tau);
        sigs = sig / chi;

        // collapse own row -> concrete x_s, v_{s+1}
        xcur = col3(xpP, xpA, xpB, alpha, beta);
        v0c  = col3(p0P, p0A, p0B, alpha, beta);
        v1c  = col3(p1P, p1A, p1B, alpha, beta);
        ((float4*)(sv0 + trow * 256))[c4] = v0c;

        // halo poll + collapse (wave 0) from slot (s-1)%3
        u64* hbp = slotp((s - 1) % 3);
        if (trow == 0) {
            if (tile > 0) {
                const u64* ra = hbp + ((size_t)(blk - 1) * BROWS) * ROWQ + 2 * c4;
                u64 a0, a1, a2, a3, a4, a5;
                for (;;) {
                    a0 = ldq(ra);            a1 = ldq(ra + 1);
                    a2 = ldq(ra + ROWQ);     a3 = ldq(ra + ROWQ + 1);
                    a4 = ldq(ra + 2 * ROWQ); a5 = ldq(ra + 2 * ROWQ + 1);
                    if (__all((a0 != SENT) && (a1 != SENT) && (a2 != SENT) &&
                              (a3 != SENT) && (a4 != SENT) && (a5 != SENT))) break;
                    __builtin_amdgcn_s_sleep(1);
                }
                vmtop = col3(unp(a0, a1), unp(a2, a3), unp(a4, a5), alpha, beta);
            }
            if (tile < 31) {
                const u64* rb = hbp + ((size_t)(blk + 1) * BROWS) * ROWQ + 2 * c4;
                u64 b0, b1, b2, b3, b4, b5, b6, b7, b8, b9, b10, b11, b12, b13, b14, b15, b16, b17;
                for (;;) {
                    b0  = ldq(rb + 3 * ROWQ);  b1  = ldq(rb + 3 * ROWQ + 1);
                    b2  = ldq(rb + 4 * ROWQ);  b3  = ldq(rb + 4 * ROWQ + 1);
                    b4  = ldq(rb + 5 * ROWQ);  b5  = ldq(rb + 5 * ROWQ + 1);
                    b6  = ldq(rb + 6 * ROWQ);  b7  = ldq(rb + 6 * ROWQ + 1);
                    b8  = ldq(rb + 7 * ROWQ);  b9  = ldq(rb + 7 * ROWQ + 1);
                    b10 = ldq(rb + 8 * ROWQ);  b11 = ldq(rb + 8 * ROWQ + 1);
                    b12 = ldq(rb + 9 * ROWQ);  b13 = ldq(rb + 9 * ROWQ + 1);
                    b14 = ldq(rb + 10 * ROWQ); b15 = ldq(rb + 10 * ROWQ + 1);
                    b16 = ldq(rb + 11 * ROWQ); b17 = ldq(rb + 11 * ROWQ + 1);
                    bool ok = (b0 != SENT) && (b1 != SENT) && (b2 != SENT) && (b3 != SENT) &&
                              (b4 != SENT) && (b5 != SENT) && (b6 != SENT) && (b7 != SENT) &&
                              (b8 != SENT) && (b9 != SENT) && (b10 != SENT) && (b11 != SENT) &&
                              (b12 != SENT) && (b13 != SENT) && (b14 != SENT) && (b15 != SENT) &&
                              (b16 != SENT) && (b17 != SENT);
                    if (__all(ok)) break;
                    __builtin_amdgcn_s_sleep(1);
                }
                v0h = col3(unp(b0, b1),   unp(b2, b3),   unp(b4, b5),   alpha, beta);
                v1h = col3(unp(b6, b7),   unp(b8, b9),   unp(b10, b11), alpha, beta);
                xoh = col3(unp(b12, b13), unp(b14, b15), unp(b16, b17), alpha, beta);
            }
        }
        asm volatile("" ::: "memory");

        // resets of slot (s+1)%3 (holds step s-2 pieces; dead after pollscale(s))
        if (s <= 47) {
            u64* rb2 = slotp((s + 1) % 3) + ((size_t)blk * BROWS) * ROWQ;
            if (trow == 0) {
                #pragma unroll
                for (int r = 3; r < 12; ++r) {
                    stq(rb2 + r * ROWQ + 2 * c4, SENT);
                    stq(rb2 + r * ROWQ + 2 * c4 + 1, SENT);
                }
            } else if (trow == 7) {
                #pragma unroll
                for (int r = 0; r < 3; ++r) {
                    stq(rb2 + r * ROWQ + 2 * c4, SENT);
                    stq(rb2 + r * ROWQ + 2 * c4 + 1, SENT);
                }
            }
        }
        wavenorm();                            // ||v_{s+1}||^2 wave partials -> pw
        barld();                               // B1: sv0 + pw visible
        pubparts(s + 1);                       // one u64 per block
        expand(slotp(s % 3), s < KSTEPS - 1);  // s=49: compute pieces, skip publishes
        tau *= chi; sig = sigs;
    }

    // ================= FINAL (step 50) =================
    pollscale(KSTEPS);                         // gate: all blocks past their piece reads
    const float opc = 1.f + chi;               // chi = chi_49
    const int iv4 = bc * 32768 + gh * 64 + c4;
    float4 xf_ = col3(xpP, xpA, xpB, alpha, beta);        // x_50
    float4 xtf = f4fma(-chi, xcur, f4s(xf_, opc));        // xcur = x_49
    st4(xout, j4, xf_);
    st4(xtout, j4, xtf);
    st4(uout, iv4, f4s(v0c, alpha));                      // u_50 = s_50 * v_50
    st4(uout, iv4 + 16384, f4s(v1c, beta));
}

extern "C" void kernel_launch(void* const* d_in, const int* in_sizes, int n_in,
                              void* d_out, int out_size, void* d_ws, size_t ws_size,
                              hipStream_t stream) {
    (void)in_sizes; (void)n_in; (void)out_size; (void)ws_size;
    const float* y     = (const float*)d_in[0];
    const float* lambd = (const float*)d_in[1];
    float* xout  = (float*)d_out;       // [0, NX)
    float* xtout = xout + NX;           // [NX, 2NX)
    float* uout  = xout + 2 * NX;       // [2NX, 2NX+NU)

    // piece slots 0,1 live in d_out (4.72 MB <= 6.29 MB; all piece reads complete
    // before final output writes, gated by the parts[50] poll). slot 2 + parts in d_ws.
    u64* h0 = (u64*)d_out;
    u64* h1 = h0 + SLOTQ;
    u64* h2 = (u64*)d_ws;
    u64* parts = h2 + SLOTQ;            // [(KSTEPS+1)][NBLK] u64

    init_ws<<<SLOTQ / 256, 256, 0, stream>>>(h0, h1, h2, parts);
    cp_persist<<<NBLK, 512, 0, stream>>>(y, lambd, xout, xtout, uout, h0, h1, h2, parts);
}